// Round 2
// baseline (7318.906 us; speedup 1.0000x reference)
//
#include <hip/hip_runtime.h>
#include <stdint.h>

// FPS: B=32 batches, P=131072 points, S=512 samples.
// Decomposition: 32 batches x 8 groups, 1024 threads/wg, 16 points/thread,
// points + running min-dists held entirely in registers.
// Per-batch 8-wg sync via monotonic device-scope atomic counter.
// Candidate slots DOUBLE-BUFFERED by step parity (fixes round-1 race:
// fast group overwrote its candidate while a slow group was still reading).

#define BATCHES 32
#define THREADS 1024
#define GROUPS  8
#define KPT     16   // points per thread = P / (GROUPS*THREADS)

__global__ void init_ws_kernel(uint32_t* arrive) {
  int t = threadIdx.x;
  if (t < BATCHES) arrive[t] = 0u;
}

__global__ __launch_bounds__(THREADS, 4)
void fps_kernel(const float* __restrict__ points,
                const int* __restrict__ nsamp_p,
                float* __restrict__ out,
                uint64_t* __restrict__ cand,
                uint32_t* __restrict__ arrive,
                int P) {
#pragma clang fp contract(off)
  const int g = blockIdx.x;   // group within batch
  const int b = blockIdx.y;   // batch
  const int t = threadIdx.x;
  const int S = nsamp_p[0];
  const int chunk = P / GROUPS;
  const int base = g * chunk;                    // first point index of this wg
  const float* pb = points + (size_t)b * P * 3;

  // Load this thread's 16 points into registers; init dists to +inf.
  float px[KPT], py[KPT], pz[KPT], dist[KPT];
#pragma unroll
  for (int k = 0; k < KPT; ++k) {
    int p = base + t + k * THREADS;
    px[k] = pb[(size_t)p * 3 + 0];
    py[k] = pb[(size_t)p * 3 + 1];
    pz[k] = pb[(size_t)p * 3 + 2];
    dist[k] = __builtin_inff();
  }

  __shared__ uint64_t wavekey[THREADS / 64];
  __shared__ float s_cx, s_cy, s_cz;
  __shared__ int s_cur;

  if (t == 0) {
    s_cur = 0;                 // reference always starts at index 0
    s_cx = pb[0]; s_cy = pb[1]; s_cz = pb[2];
  }
  __syncthreads();

  float* out_idx = out;                        // [B][S] indices as f32
  float* out_pts = out + (size_t)BATCHES * S;  // [B][S][3]

  // cand layout: [BATCHES][2][GROUPS] (parity double-buffer)
  uint64_t* cand_b = cand + (size_t)b * 2 * GROUPS;
  uint32_t* arr_b  = arrive + b;

  for (int s = 0; s < S; ++s) {
    const float cx = s_cx, cy = s_cy, cz = s_cz;
    const int cur = s_cur;

    if (g == 0 && t == 0) {
      out_idx[(size_t)b * S + s] = (float)cur;
      size_t o = ((size_t)b * S + s) * 3;
      out_pts[o + 0] = cx; out_pts[o + 1] = cy; out_pts[o + 2] = cz;
    }

    // Update running min-dists and find local (max dist, first index).
    float bd = -1.0f;
    int bi = 0;
#pragma unroll
    for (int k = 0; k < KPT; ++k) {
      float dx = px[k] - cx;
      float dy = py[k] - cy;
      float dz = pz[k] - cz;
      float d = (dx * dx + dy * dy) + dz * dz;   // numpy order, no FMA (contract off)
      float nd = dist[k] < d ? dist[k] : d;      // jnp.minimum
      dist[k] = nd;
      if (nd > bd) { bd = nd; bi = base + t + k * THREADS; }  // k asc => idx asc => first-max
    }

    // Pack (dist, ~idx): u64 max == max dist, ties -> smallest index.
    unsigned long long key =
        ((unsigned long long)__float_as_uint(bd) << 32) |
        (unsigned long long)(~(uint32_t)bi);

    // Wave (64-lane) max-reduce.
#pragma unroll
    for (int off = 32; off > 0; off >>= 1) {
      unsigned long long o = __shfl_down(key, (unsigned)off, 64);
      if (o > key) key = o;
    }
    if ((t & 63) == 0) wavekey[t >> 6] = key;
    __syncthreads();

    if (t == 0) {
      unsigned long long k0 = wavekey[0];
#pragma unroll
      for (int w = 1; w < THREADS / 64; ++w) {
        unsigned long long kw = wavekey[w];
        if (kw > k0) k0 = kw;
      }
      uint64_t* slot = cand_b + (size_t)(s & 1) * GROUPS;
      // Publish this group's candidate, then arrive (release).
      __hip_atomic_store(&slot[g], (uint64_t)k0, __ATOMIC_RELAXED,
                         __HIP_MEMORY_SCOPE_AGENT);
      __hip_atomic_fetch_add(arr_b, 1u, __ATOMIC_RELEASE,
                             __HIP_MEMORY_SCOPE_AGENT);
      const uint32_t target = (uint32_t)(GROUPS * (s + 1));
      while (__hip_atomic_load(arr_b, __ATOMIC_ACQUIRE,
                               __HIP_MEMORY_SCOPE_AGENT) < target) {
        __builtin_amdgcn_s_sleep(1);
      }
      // Reduce the 8 candidates; extract winner index; fetch its coords.
      uint64_t best = 0;
#pragma unroll
      for (int q = 0; q < GROUPS; ++q) {
        uint64_t kq = __hip_atomic_load(&slot[q], __ATOMIC_RELAXED,
                                        __HIP_MEMORY_SCOPE_AGENT);
        if (kq > best) best = kq;
      }
      int widx = (int)(~(uint32_t)best);
      s_cur = widx;
      s_cx = pb[(size_t)widx * 3 + 0];
      s_cy = pb[(size_t)widx * 3 + 1];
      s_cz = pb[(size_t)widx * 3 + 2];
    }
    __syncthreads();
  }
}

extern "C" void kernel_launch(void* const* d_in, const int* in_sizes, int n_in,
                              void* d_out, int out_size, void* d_ws, size_t ws_size,
                              hipStream_t stream) {
  const float* points = (const float*)d_in[0];
  const int* nsamples = (const int*)d_in[1];
  // d_in[2] = kd_depth: only affects internal partitioning in the original
  // CUDA kernel; math identical. Ignored.

  const int P = in_sizes[0] / (BATCHES * 3);   // 131072

  uint64_t* cand   = (uint64_t*)d_ws;   // [BATCHES][2][GROUPS]
  uint32_t* arrive = (uint32_t*)((char*)d_ws + (size_t)BATCHES * 2 * GROUPS * sizeof(uint64_t));

  hipLaunchKernelGGL(init_ws_kernel, dim3(1), dim3(64), 0, stream, arrive);

  dim3 grid(GROUPS, BATCHES);
  hipLaunchKernelGGL(fps_kernel, grid, dim3(THREADS), 0, stream,
                     points, nsamples, (float*)d_out, cand, arrive, P);
}

// Round 3
// 6610.487 us; speedup vs baseline: 1.1072x; 1.1072x over previous
//
#include <hip/hip_runtime.h>
#include <stdint.h>

// FPS: B=32 batches, P=131072 points, S=512 samples.
// 32 batches x 8 groups, 1024 threads/wg, 16 points/thread; points + running
// min-dists in registers. Per-batch 8-wg sync via padded monotonic counter.
// Round-3 changes vs round-2 (which passed, 7.24ms):
//  - arrive counters padded to one 128B line per batch (was: all 32 in 1 line)
//  - XCD swizzle: all 8 groups of a batch on the same XCD (l%8 == b%8)
//  - candidate records carry winner coords (no dependent points re-fetch)

#define BATCHES 32
#define THREADS 1024
#define GROUPS  8
#define KPT     16            // P / (GROUPS*THREADS)
#define ARR_STRIDE 32         // u32 per batch slot = 128B line
#define SLOT_U64 4            // 32B per (batch,parity,group) record

__global__ void init_ws_kernel(uint32_t* arrive) {
  int t = threadIdx.x;        // 1024 threads zero 32*ARR_STRIDE u32
  if (t < BATCHES * ARR_STRIDE) arrive[t] = 0u;
}

__global__ __launch_bounds__(THREADS, 4)
void fps_kernel(const float* __restrict__ points,
                const int* __restrict__ nsamp_p,
                float* __restrict__ out,
                uint64_t* __restrict__ cand,
                uint32_t* __restrict__ arrive,
                int P) {
#pragma clang fp contract(off)
  // Decode so that linear id % 8 == batch % 8  (round-robin XCD => all groups
  // of a batch share an XCD; performance heuristic only).
  const int l = blockIdx.x;
  const int xcd = l & 7;
  const int m = l >> 3;
  const int b = xcd + ((m & 3) << 3);   // batch
  const int g = m >> 2;                 // group within batch
  const int t = threadIdx.x;
  const int S = nsamp_p[0];
  const int base = g * (P / GROUPS);
  const float* pb = points + (size_t)b * P * 3;

  // This thread's 16 points + running min-dists, all in registers.
  float px[KPT], py[KPT], pz[KPT], dist[KPT];
#pragma unroll
  for (int k = 0; k < KPT; ++k) {
    int p = base + t + k * THREADS;
    px[k] = pb[(size_t)p * 3 + 0];
    py[k] = pb[(size_t)p * 3 + 1];
    pz[k] = pb[(size_t)p * 3 + 2];
    dist[k] = __builtin_inff();
  }

  __shared__ uint64_t sk[THREADS / 64];
  __shared__ float sx[THREADS / 64], sy[THREADS / 64], sz[THREADS / 64];
  __shared__ float s_cx, s_cy, s_cz;
  __shared__ int s_cur;

  if (t == 0) {
    s_cur = 0;                 // reference always starts at index 0
    s_cx = pb[0]; s_cy = pb[1]; s_cz = pb[2];
  }
  __syncthreads();

  float* out_idx = out;                        // [B][S] indices as f32
  float* out_pts = out + (size_t)BATCHES * S;  // [B][S][3]

  uint64_t* cand_b = cand + (size_t)b * 2 * GROUPS * SLOT_U64;
  uint32_t* arr_b  = arrive + (size_t)b * ARR_STRIDE;

  for (int s = 0; s < S; ++s) {
    const float cx = s_cx, cy = s_cy, cz = s_cz;
    const int cur = s_cur;

    if (g == 0 && t == 0) {
      out_idx[(size_t)b * S + s] = (float)cur;
      size_t o = ((size_t)b * S + s) * 3;
      out_pts[o + 0] = cx; out_pts[o + 1] = cy; out_pts[o + 2] = cz;
    }

    // Update running min-dists; local (max dist, first index) + its coords.
    float bd = -1.0f, bx = 0.f, by = 0.f, bz = 0.f;
    int bi = 0;
#pragma unroll
    for (int k = 0; k < KPT; ++k) {
      float dx = px[k] - cx;
      float dy = py[k] - cy;
      float dz = pz[k] - cz;
      float d = (dx * dx + dy * dy) + dz * dz;   // numpy order, no FMA
      float nd = dist[k] < d ? dist[k] : d;      // jnp.minimum
      dist[k] = nd;
      if (nd > bd) { bd = nd; bi = base + t + k * THREADS;
                     bx = px[k]; by = py[k]; bz = pz[k]; }
    }

    // Pack (dist, ~idx): u64 max == max dist, ties -> smallest index.
    unsigned long long key =
        ((unsigned long long)__float_as_uint(bd) << 32) |
        (unsigned long long)(~(uint32_t)bi);

    // Wave max-reduce of (key, coords).
#pragma unroll
    for (int off = 32; off > 0; off >>= 1) {
      unsigned long long ok = __shfl_down(key, (unsigned)off, 64);
      float ox = __shfl_down(bx, (unsigned)off, 64);
      float oy = __shfl_down(by, (unsigned)off, 64);
      float oz = __shfl_down(bz, (unsigned)off, 64);
      if (ok > key) { key = ok; bx = ox; by = oy; bz = oz; }
    }
    if ((t & 63) == 0) { int w = t >> 6; sk[w] = key; sx[w] = bx; sy[w] = by; sz[w] = bz; }
    __syncthreads();

    if (t == 0) {
      unsigned long long k0 = sk[0];
      float gx = sx[0], gy = sy[0], gz = sz[0];
#pragma unroll
      for (int w = 1; w < THREADS / 64; ++w) {
        if (sk[w] > k0) { k0 = sk[w]; gx = sx[w]; gy = sy[w]; gz = sz[w]; }
      }
      // Publish (key, coords) record, then arrive (release).
      uint64_t* slot = cand_b + (size_t)(s & 1) * GROUPS * SLOT_U64 + (size_t)g * SLOT_U64;
      uint64_t xy = ((uint64_t)__float_as_uint(gy) << 32) | __float_as_uint(gx);
      __hip_atomic_store(&slot[0], (uint64_t)k0, __ATOMIC_RELAXED, __HIP_MEMORY_SCOPE_AGENT);
      __hip_atomic_store(&slot[1], xy,           __ATOMIC_RELAXED, __HIP_MEMORY_SCOPE_AGENT);
      __hip_atomic_store(&slot[2], (uint64_t)__float_as_uint(gz), __ATOMIC_RELAXED, __HIP_MEMORY_SCOPE_AGENT);
      __hip_atomic_fetch_add(arr_b, 1u, __ATOMIC_RELEASE, __HIP_MEMORY_SCOPE_AGENT);
      const uint32_t target = (uint32_t)(GROUPS * (s + 1));
      while (__hip_atomic_load(arr_b, __ATOMIC_ACQUIRE, __HIP_MEMORY_SCOPE_AGENT) < target) {
        __builtin_amdgcn_s_sleep(1);
      }
      // Reduce the 8 records; winner idx + coords come straight from records.
      const uint64_t* rb = cand_b + (size_t)(s & 1) * GROUPS * SLOT_U64;
      uint64_t rk[GROUPS], rxy[GROUPS], rz[GROUPS];
#pragma unroll
      for (int q = 0; q < GROUPS; ++q) {
        const uint64_t* sq = rb + (size_t)q * SLOT_U64;
        rk[q]  = __hip_atomic_load(&sq[0], __ATOMIC_RELAXED, __HIP_MEMORY_SCOPE_AGENT);
        rxy[q] = __hip_atomic_load(&sq[1], __ATOMIC_RELAXED, __HIP_MEMORY_SCOPE_AGENT);
        rz[q]  = __hip_atomic_load(&sq[2], __ATOMIC_RELAXED, __HIP_MEMORY_SCOPE_AGENT);
      }
      uint64_t best = rk[0]; uint64_t bxy = rxy[0]; uint64_t bzz = rz[0];
#pragma unroll
      for (int q = 1; q < GROUPS; ++q) {
        if (rk[q] > best) { best = rk[q]; bxy = rxy[q]; bzz = rz[q]; }
      }
      s_cur = (int)(~(uint32_t)best);
      s_cx = __uint_as_float((uint32_t)bxy);
      s_cy = __uint_as_float((uint32_t)(bxy >> 32));
      s_cz = __uint_as_float((uint32_t)bzz);
    }
    __syncthreads();
  }
}

extern "C" void kernel_launch(void* const* d_in, const int* in_sizes, int n_in,
                              void* d_out, int out_size, void* d_ws, size_t ws_size,
                              hipStream_t stream) {
  const float* points = (const float*)d_in[0];
  const int* nsamples = (const int*)d_in[1];
  // d_in[2] = kd_depth: acceleration parameter only; math identical. Ignored.

  const int P = in_sizes[0] / (BATCHES * 3);   // 131072

  // ws: cand [32][2][8] records of 32B = 16KB, then arrive 32*128B = 4KB.
  uint64_t* cand   = (uint64_t*)d_ws;
  uint32_t* arrive = (uint32_t*)((char*)d_ws +
                     (size_t)BATCHES * 2 * GROUPS * SLOT_U64 * sizeof(uint64_t));

  hipLaunchKernelGGL(init_ws_kernel, dim3(1), dim3(THREADS), 0, stream, arrive);

  dim3 grid(GROUPS * BATCHES);
  hipLaunchKernelGGL(fps_kernel, grid, dim3(THREADS), 0, stream,
                     points, nsamples, (float*)d_out, cand, arrive, P);
}

// Round 4
// 3720.667 us; speedup vs baseline: 1.9671x; 1.7767x over previous
//
#include <hip/hip_runtime.h>
#include <stdint.h>

// FPS: B=32 batches, P=131072 points, S=512 samples.
// 32 batches x 8 groups, 1024 threads/wg, 16 points/thread.
// px/py/pz in VGPRs (waves_per_eu pinned 4,4 => 128-reg budget, no remat),
// running min-dists in LDS. Per-batch sync: each group release-stores one
// self-tagged 64B record; wave0 lanes 0-7 poll all 8 records in parallel.
// Records parity-double-buffered (overwrite-safety: a slot for step s+2 is
// only written after its writer observed all step-s+1 tags, which implies
// every group finished reading the step-s slot).

#define BATCHES 32
#define THREADS 1024
#define GROUPS  8
#define KPT     16            // P / (GROUPS*THREADS)
#define REC_U64 8             // 64B per record (padded: no false sharing)
#define IDX_MASK 0x1FFFFu     // 17 bits: P=131072
#define TAG_SHIFT 22
#define TAG_MASK 0x3FFu       // 10 bits: S+1 <= 513

__global__ void init_ws_kernel(uint64_t* cand) {
  // zero [BATCHES][2][GROUPS][REC_U64] = 4096 u64 (clears 0xAA poison tags)
  int t = threadIdx.x;
  for (int i = t; i < BATCHES * 2 * GROUPS * REC_U64; i += THREADS)
    cand[i] = 0ull;
}

__global__ __attribute__((amdgpu_flat_work_group_size(THREADS, THREADS),
                          amdgpu_waves_per_eu(4, 4)))
void fps_kernel(const float* __restrict__ points,
                const int* __restrict__ nsamp_p,
                float* __restrict__ out,
                uint64_t* __restrict__ cand,
                int P) {
#pragma clang fp contract(off)
  // linear id % 8 == batch % 8: all 8 groups of a batch on one XCD (heuristic)
  const int l = blockIdx.x;
  const int m = l >> 3;
  const int b = (l & 7) + ((m & 3) << 3);   // batch
  const int g = m >> 2;                     // group within batch
  const int t = threadIdx.x;
  const int S = nsamp_p[0];
  const int base = g * (P / GROUPS);
  const float* pb = points + (size_t)b * P * 3;

  __shared__ float sdist[KPT * THREADS];    // 64KB; bank = t%32 (2-way, free)
  __shared__ uint64_t sk[THREADS / 64];
  __shared__ float sx[THREADS / 64], sy[THREADS / 64], sz[THREADS / 64];
  __shared__ float s_cx, s_cy, s_cz;
  __shared__ int s_cur;

  // Load this thread's 16 points into registers; dists to LDS (+inf).
  float px[KPT], py[KPT], pz[KPT];
#pragma unroll
  for (int k = 0; k < KPT; ++k) {
    int p = base + t + k * THREADS;
    px[k] = pb[(size_t)p * 3 + 0];
    py[k] = pb[(size_t)p * 3 + 1];
    pz[k] = pb[(size_t)p * 3 + 2];
    sdist[k * THREADS + t] = __builtin_inff();
  }
  if (t == 0) {
    s_cur = 0;                 // reference always starts at index 0
    s_cx = pb[0]; s_cy = pb[1]; s_cz = pb[2];
  }
  __syncthreads();

  float* out_idx = out;                        // [B][S] indices as f32
  float* out_pts = out + (size_t)BATCHES * S;  // [B][S][3]

  for (int s = 0; s < S; ++s) {
    const float cx = s_cx, cy = s_cy, cz = s_cz;
    const int cur = s_cur;
    const uint32_t tag = (uint32_t)(s + 1);

    if (g == 0 && t == 0) {
      out_idx[(size_t)b * S + s] = (float)cur;
      size_t o = ((size_t)b * S + s) * 3;
      out_pts[o + 0] = cx; out_pts[o + 1] = cy; out_pts[o + 2] = cz;
    }

    // Update running min-dists (LDS); local (max dist, first index) + coords.
    float bd = -1.0f, bx = 0.f, by = 0.f, bz = 0.f;
    int bi = 0;
#pragma unroll
    for (int k = 0; k < KPT; ++k) {
      float dx = px[k] - cx;
      float dy = py[k] - cy;
      float dz = pz[k] - cz;
      float d = (dx * dx + dy * dy) + dz * dz;   // numpy order, no FMA
      float od = sdist[k * THREADS + t];
      float nd = od < d ? od : d;                // jnp.minimum
      sdist[k * THREADS + t] = nd;
      if (nd > bd) { bd = nd; bi = base + t + k * THREADS;
                     bx = px[k]; by = py[k]; bz = pz[k]; }
    }

    // combo: [distbits:32][tag:10][0:5][~idx:17]; same-step combos compare as
    // (dist desc, idx asc). bd >= 0 so distbits is order-preserving.
    unsigned long long key =
        ((unsigned long long)__float_as_uint(bd) << 32) |
        ((unsigned long long)tag << TAG_SHIFT) |
        (unsigned long long)((~(uint32_t)bi) & IDX_MASK);

    // Wave max-reduce of (key, coords).
#pragma unroll
    for (int off = 32; off > 0; off >>= 1) {
      unsigned long long ok = __shfl_down(key, (unsigned)off, 64);
      float ox = __shfl_down(bx, (unsigned)off, 64);
      float oy = __shfl_down(by, (unsigned)off, 64);
      float oz = __shfl_down(bz, (unsigned)off, 64);
      if (ok > key) { key = ok; bx = ox; by = oy; bz = oz; }
    }
    if ((t & 63) == 0) { int w = t >> 6; sk[w] = key; sx[w] = bx; sy[w] = by; sz[w] = bz; }
    __syncthreads();

    if (t < 64) {
      // Gather the 16 wave results into lanes 0-15, reduce in-wave.
      unsigned long long k2 = (t < THREADS / 64) ? sk[t] : 0ull;
      float gx = (t < THREADS / 64) ? sx[t] : 0.f;
      float gy = (t < THREADS / 64) ? sy[t] : 0.f;
      float gz = (t < THREADS / 64) ? sz[t] : 0.f;
#pragma unroll
      for (int off = 8; off > 0; off >>= 1) {
        unsigned long long ok = __shfl_down(k2, (unsigned)off, 64);
        float ox = __shfl_down(gx, (unsigned)off, 64);
        float oy = __shfl_down(gy, (unsigned)off, 64);
        float oz = __shfl_down(gz, (unsigned)off, 64);
        if (ok > k2) { k2 = ok; gx = ox; gy = oy; gz = oz; }
      }
      uint64_t* recs = cand + (((size_t)b * 2 + (s & 1)) * GROUPS) * REC_U64;
      if (t == 0) {
        // Publish: coords relaxed, then self-tagged combo with release.
        uint64_t* slot = recs + (size_t)g * REC_U64;
        uint64_t xy = ((uint64_t)__float_as_uint(gy) << 32) | __float_as_uint(gx);
        __hip_atomic_store(&slot[1], xy, __ATOMIC_RELAXED, __HIP_MEMORY_SCOPE_AGENT);
        __hip_atomic_store(&slot[2], (uint64_t)__float_as_uint(gz),
                           __ATOMIC_RELAXED, __HIP_MEMORY_SCOPE_AGENT);
        __hip_atomic_store(&slot[0], (uint64_t)k2, __ATOMIC_RELEASE,
                           __HIP_MEMORY_SCOPE_AGENT);
      }
      // Lanes 0-7 poll the 8 records in parallel until step tag matches.
      int done = (t < GROUPS) ? 0 : 1;
      unsigned long long v = 0;
      const uint64_t* myrec = recs + (size_t)(t & (GROUPS - 1)) * REC_U64;
      while (!__all(done)) {
        if (!done) {
          v = __hip_atomic_load(&myrec[0], __ATOMIC_ACQUIRE, __HIP_MEMORY_SCOPE_AGENT);
          done = (((uint32_t)(v >> TAG_SHIFT) & TAG_MASK) == tag);
        }
        if (!__all(done)) __builtin_amdgcn_s_sleep(1);
      }
      unsigned long long vxy = 0, vz = 0;
      if (t < GROUPS) {
        vxy = __hip_atomic_load(&myrec[1], __ATOMIC_RELAXED, __HIP_MEMORY_SCOPE_AGENT);
        vz  = __hip_atomic_load(&myrec[2], __ATOMIC_RELAXED, __HIP_MEMORY_SCOPE_AGENT);
      } else { v = 0; }
      // Reduce 8 records (lanes 0-7) in-wave.
#pragma unroll
      for (int off = 4; off > 0; off >>= 1) {
        unsigned long long ok = __shfl_down(v, (unsigned)off, 64);
        unsigned long long oxy = __shfl_down(vxy, (unsigned)off, 64);
        unsigned long long oz = __shfl_down(vz, (unsigned)off, 64);
        if (ok > v) { v = ok; vxy = oxy; vz = oz; }
      }
      if (t == 0) {
        s_cur = (int)((~(uint32_t)v) & IDX_MASK);
        s_cx = __uint_as_float((uint32_t)vxy);
        s_cy = __uint_as_float((uint32_t)(vxy >> 32));
        s_cz = __uint_as_float((uint32_t)vz);
      }
    }
    __syncthreads();
  }
}

extern "C" void kernel_launch(void* const* d_in, const int* in_sizes, int n_in,
                              void* d_out, int out_size, void* d_ws, size_t ws_size,
                              hipStream_t stream) {
  const float* points = (const float*)d_in[0];
  const int* nsamples = (const int*)d_in[1];
  // d_in[2] = kd_depth: acceleration parameter only; math identical. Ignored.

  const int P = in_sizes[0] / (BATCHES * 3);   // 131072

  uint64_t* cand = (uint64_t*)d_ws;   // [32][2][8] x 64B = 32KB

  hipLaunchKernelGGL(init_ws_kernel, dim3(1), dim3(THREADS), 0, stream, cand);

  dim3 grid(GROUPS * BATCHES);
  hipLaunchKernelGGL(fps_kernel, grid, dim3(THREADS), 0, stream,
                     points, nsamples, (float*)d_out, cand, P);
}

// Round 5
// 1878.855 us; speedup vs baseline: 3.8954x; 1.9803x over previous
//
#include <hip/hip_runtime.h>
#include <stdint.h>

// FPS: B=32 batches, P=131072 points, S=512 samples.
// 32 batches x 8 groups, 1024 threads/wg, 16 points/thread.
// Points in VGPRs, running min-dists in LDS (thread-private slots).
// Per step (ONE __syncthreads):
//   update -> two-phase wave reduce (max dist u32, then max ~idx among tied)
//   lane0 writes 8B combo [distbits:32][tag:10][~idx:17] to LDS sk[parity][wave]
//   barrier; every wave gathers+reduces the 16 combos; t==0 relaxed-stores the
//   group combo to the batch's 128B record line; ALL waves poll the 8 records
//   (lanes 0-7, relaxed, no fence needed -- combo is self-contained), reduce,
//   then every wave fetches winner coords from points[] (uniform-address load).
// Overwrite safety: slot for step s+2 is written only after its writer's poll
// at s+1 observed all tags s+2... (data-dep + barrier chain; records parity-
// double-buffered, tags 1..512 never repeat within a slot).

#define BATCHES 32
#define THREADS 1024
#define GROUPS  8
#define KPT     16            // P / (GROUPS*THREADS)
#define IDX_MASK 0x1FFFFu     // 17 bits: P=131072
#define TAG_SHIFT 22
#define TAG_MASK 0x3FFu       // 10 bits: tags 1..512 (0xAA poison tag=682, no match)
#define LINE_U64 16           // 128B per (batch,parity) record line

__global__ void init_ws_kernel(uint64_t* cand) {
  int t = threadIdx.x;        // BATCHES*2*LINE_U64 = 1024 exactly
  cand[t] = 0ull;
}

__global__ __attribute__((amdgpu_flat_work_group_size(THREADS, THREADS),
                          amdgpu_waves_per_eu(4, 4)))
void fps_kernel(const float* __restrict__ points,
                const int* __restrict__ nsamp_p,
                float* __restrict__ out,
                uint64_t* __restrict__ cand,
                int P) {
#pragma clang fp contract(off)
  // linear id % 8 == batch % 8: all 8 groups of a batch on one XCD (heuristic)
  const int l = blockIdx.x;
  const int m = l >> 3;
  const int b = (l & 7) + ((m & 3) << 3);   // batch
  const int g = m >> 2;                     // group within batch
  const int t = threadIdx.x;
  const int lane = t & 63;
  const int w = t >> 6;
  const int S = nsamp_p[0];
  const int base = g * (P / GROUPS);
  const float* pb = points + (size_t)b * P * 3;

  __shared__ float sdist[KPT * THREADS];    // thread-private slots (no sync needed)
  __shared__ uint64_t sk[2][THREADS / 64];  // per-wave combos, parity dbuf

  // This thread's 16 points into registers; dists to LDS (+inf).
  float px[KPT], py[KPT], pz[KPT];
#pragma unroll
  for (int k = 0; k < KPT; ++k) {
    int p = base + t + k * THREADS;
    px[k] = pb[(size_t)p * 3 + 0];
    py[k] = pb[(size_t)p * 3 + 1];
    pz[k] = pb[(size_t)p * 3 + 2];
    sdist[k * THREADS + t] = __builtin_inff();
  }

  // Wave-carried current state (wave-uniform registers, no LDS broadcast).
  int cur = 0;                 // reference always starts at index 0
  float cx = pb[0], cy = pb[1], cz = pb[2];

  float* out_idx = out;                        // [B][S] indices as f32
  float* out_pts = out + (size_t)BATCHES * S;  // [B][S][3]

  uint64_t* line_base = cand + (size_t)b * 2 * LINE_U64;

  for (int s = 0; s < S; ++s) {
    const uint32_t tag = (uint32_t)(s + 1);

    // ---- update running min-dists; per-thread (max dist, first index) ----
    float bd = -1.0f;
    int bi = 0;
#pragma unroll
    for (int k = 0; k < KPT; ++k) {
      float dx = px[k] - cx;
      float dy = py[k] - cy;
      float dz = pz[k] - cz;
      float d = (dx * dx + dy * dy) + dz * dz;   // numpy order, no FMA
      float od = sdist[k * THREADS + t];
      float nd = od < d ? od : d;                // jnp.minimum
      sdist[k * THREADS + t] = nd;
      if (nd > bd) { bd = nd; bi = base + t + k * THREADS; }  // k asc => first-max
    }

    // ---- two-phase wave reduce: max distbits, then max ~idx among tied ----
    const uint32_t mydb = __float_as_uint(bd);   // bd >= 0 => order-preserving
    uint32_t db = mydb;
#pragma unroll
    for (int off = 1; off < 64; off <<= 1) {
      uint32_t o = __shfl_xor(db, off, 64);
      db = o > db ? o : db;
    }
    uint32_t mk = (mydb == db) ? ~(uint32_t)bi : 0u;  // ~bi: high 15 bits set
#pragma unroll
    for (int off = 1; off < 64; off <<= 1) {
      uint32_t o = __shfl_xor(mk, off, 64);
      mk = o > mk ? o : mk;
    }
    // combo: [distbits:32][tag:10][0:5][~idx:17]
    if (lane == 0) {
      sk[s & 1][w] = ((unsigned long long)db << 32) |
                     ((unsigned long long)tag << TAG_SHIFT) |
                     (unsigned long long)(mk & IDX_MASK);
    }
    __syncthreads();   // the only barrier per step

    // ---- every wave: gather 16 wave combos, reduce to group combo ----
    unsigned long long gc = (lane < THREADS / 64) ? sk[s & 1][lane] : 0ull;
#pragma unroll
    for (int off = 1; off < 16; off <<= 1) {
      unsigned long long o = __shfl_xor(gc, off, 64);
      if (o > gc) gc = o;    // lanes 0-15 end with the true group combo
    }

    uint64_t* line = line_base + (size_t)(s & 1) * LINE_U64;
    if (t == 0) {
      // Relaxed is safe: combo is self-contained; data-dep chain through the
      // poll of step s-1 orders this store after all reads of this slot.
      __hip_atomic_store(&line[g], (uint64_t)gc, __ATOMIC_RELAXED,
                         __HIP_MEMORY_SCOPE_AGENT);
    }
    if (g == 0 && t == 0) {    // overlapped with other groups' publish/poll
      out_idx[(size_t)b * S + s] = (float)cur;
      size_t o = ((size_t)b * S + s) * 3;
      out_pts[o + 0] = cx; out_pts[o + 1] = cy; out_pts[o + 2] = cz;
    }

    // ---- all waves poll the 8 records (lanes 0-7, relaxed, no fence) ----
    unsigned long long v = 0;
    int done = (lane < GROUPS) ? 0 : 1;
    while (!__all(done)) {
      if (!done) {
        v = __hip_atomic_load(&line[lane], __ATOMIC_RELAXED,
                              __HIP_MEMORY_SCOPE_AGENT);
        done = (((uint32_t)(v >> TAG_SHIFT) & TAG_MASK) == tag);
      }
      if (!__all(done)) __builtin_amdgcn_s_sleep(1);
    }
    // reduce the 8 combos (lanes 0-7 hold them; others neutral 0)
#pragma unroll
    for (int off = 1; off < 8; off <<= 1) {
      unsigned long long o = __shfl_xor(v, off, 64);
      if (o > v) v = o;
    }
    v = __shfl(v, 0, 64);      // broadcast lane0's true result to all lanes

    // ---- winner index + coords (uniform-address load, one txn per wave) ----
    cur = (int)((~(uint32_t)v) & IDX_MASK);
    const float* wp = pb + (size_t)cur * 3;
    cx = wp[0]; cy = wp[1]; cz = wp[2];
  }
}

extern "C" void kernel_launch(void* const* d_in, const int* in_sizes, int n_in,
                              void* d_out, int out_size, void* d_ws, size_t ws_size,
                              hipStream_t stream) {
  const float* points = (const float*)d_in[0];
  const int* nsamples = (const int*)d_in[1];
  // d_in[2] = kd_depth: acceleration parameter only; math identical. Ignored.

  const int P = in_sizes[0] / (BATCHES * 3);   // 131072

  uint64_t* cand = (uint64_t*)d_ws;   // [32][2][16 u64] = 8KB (only [..][8] used)

  hipLaunchKernelGGL(init_ws_kernel, dim3(1), dim3(BATCHES * 2 * LINE_U64),
                     0, stream, cand);

  dim3 grid(GROUPS * BATCHES);
  hipLaunchKernelGGL(fps_kernel, grid, dim3(THREADS), 0, stream,
                     points, nsamples, (float*)d_out, cand, P);
}